// Round 5
// baseline (70.035 us; speedup 1.0000x reference)
//
#include <hip/hip_runtime.h>

// anchors: (8192, 8, 768) fp32 = [n=8192 rows][COLS=6144 cols]
// loss = -((2*n*sum(a^2) - 2*dot(colsum, colsum)) / sqrt(768)) / (8*8)
//
// Single fused kernel, fence-free last-block finalize:
//  - col_sum accumulated via fp32 atomicAdd into 8 replicas (contention /8)
//  - release: inline `s_waitcnt vmcnt(0)` after our atomics, then RELAXED
//    agent-scope counter increment (atomics resolve at the memory-side
//    coherence point; no cache writeback needed)
//  - acquire: last block reads replicas via RELAXED agent-scope atomic
//    loads (bypass local L1/L2), so no invalidate needed.
// R3's regression was nt-loads + per-block __threadfence(); both removed.

typedef float f32x4 __attribute__((ext_vector_type(4)));

constexpr int COLS   = 6144;       // k * dim_emb = 8 * 768
constexpr int COLS4  = COLS / 4;   // 1536 float4 per row
constexpr int BLK    = 256;
constexpr int STRIPS = COLS4 / BLK;        // 6 column strips
constexpr int ROWS_PER_CHUNK = 64;         // 128 chunks -> 768 blocks
constexpr int NREP   = 8;                  // col_sum replicas

__global__ void __launch_bounds__(BLK)
anchor_fused(const f32x4* __restrict__ a,
             float* __restrict__ colrep,      // ws[0 .. NREP*COLS)
             float* __restrict__ sum_sq,      // ws[NREP*COLS]
             unsigned* __restrict__ counter,  // ws[NREP*COLS+1]
             float* __restrict__ out, int n_rows) {
    const int col4 = blockIdx.x * BLK + threadIdx.x;   // 0..COLS4-1
    const int row0 = blockIdx.y * ROWS_PER_CHUNK;
    const f32x4* p = a + (size_t)row0 * COLS4 + col4;
    const unsigned nblocks = gridDim.x * gridDim.y;

    f32x4 cs = (f32x4)(0.f);
    float ssq = 0.f;
    #pragma unroll 8
    for (int r = 0; r < ROWS_PER_CHUNK; ++r) {
        f32x4 v = p[(size_t)r * COLS4];
        cs += v;
        ssq = fmaf(v.x, v.x, ssq);
        ssq = fmaf(v.y, v.y, ssq);
        ssq = fmaf(v.z, v.z, ssq);
        ssq = fmaf(v.w, v.w, ssq);
    }

    float* c = colrep + (blockIdx.y & (NREP - 1)) * COLS + col4 * 4;
    atomicAdd(c + 0, cs.x);
    atomicAdd(c + 1, cs.y);
    atomicAdd(c + 2, cs.z);
    atomicAdd(c + 3, cs.w);

    // block-reduce ssq -> one atomic per block
    #pragma unroll
    for (int off = 32; off > 0; off >>= 1)
        ssq += __shfl_down(ssq, off, 64);
    __shared__ float wsum[BLK / 64];
    const int lane = threadIdx.x & 63, wid = threadIdx.x >> 6;
    if (lane == 0) wsum[wid] = ssq;
    __syncthreads();
    if (threadIdx.x == 0) {
        float s = 0.f;
        #pragma unroll
        for (int w = 0; w < BLK / 64; ++w) s += wsum[w];
        atomicAdd(sum_sq, s);
    }

    // ---- fence-free last-block handoff ----
    __shared__ int is_last;
    if (threadIdx.x == 0) {
        asm volatile("s_waitcnt vmcnt(0)" ::: "memory");  // our atomics done
        unsigned prev = __hip_atomic_fetch_add(counter, 1u, __ATOMIC_RELAXED,
                                               __HIP_MEMORY_SCOPE_AGENT);
        is_last = (prev == nblocks - 1);
    }
    __syncthreads();
    if (!is_last) return;

    // last block: dot(colsum, colsum) over the 8 replicas
    float dot = 0.f;
    for (int col = threadIdx.x; col < COLS; col += BLK) {
        float s = 0.f;
        #pragma unroll
        for (int r = 0; r < NREP; ++r)
            s += __hip_atomic_load(&colrep[r * COLS + col], __ATOMIC_RELAXED,
                                   __HIP_MEMORY_SCOPE_AGENT);
        dot = fmaf(s, s, dot);
    }
    #pragma unroll
    for (int off = 32; off > 0; off >>= 1)
        dot += __shfl_down(dot, off, 64);
    if (lane == 0) wsum[wid] = dot;
    __syncthreads();
    if (threadIdx.x == 0) {
        float d = 0.f;
        #pragma unroll
        for (int w = 0; w < BLK / 64; ++w) d += wsum[w];
        float s = __hip_atomic_load(sum_sq, __ATOMIC_RELAXED,
                                    __HIP_MEMORY_SCOPE_AGENT);
        double pair = 2.0 * (double)n_rows * (double)s - 2.0 * (double)d;
        const double factor = 27.712812921102035;  // sqrt(768)
        out[0] = (float)(-(pair / factor) / 64.0); // k*k = 64
    }
}

extern "C" void kernel_launch(void* const* d_in, const int* in_sizes, int n_in,
                              void* d_out, int out_size, void* d_ws, size_t ws_size,
                              hipStream_t stream) {
    const f32x4* a = (const f32x4*)d_in[0];
    float* ws      = (float*)d_ws;
    float* out     = (float*)d_out;
    const int n_rows = in_sizes[0] / COLS;  // 8192

    (void)hipMemsetAsync(d_ws, 0, (NREP * COLS + 2) * sizeof(float), stream);

    dim3 grid(STRIPS, n_rows / ROWS_PER_CHUNK);
    anchor_fused<<<grid, BLK, 0, stream>>>(
        a, ws, ws + NREP * COLS, (unsigned*)(ws + NREP * COLS + 1), out, n_rows);
}

// Round 6
// 46.353 us; speedup vs baseline: 1.5109x; 1.5109x over previous
//
#include <hip/hip_runtime.h>

// anchors: (8192, 8, 768) fp32 = [n=8192 rows][COLS=6144 cols]
// loss = -((2*n*sum(a^2) - 2*dot(colsum, colsum)) / sqrt(768)) / (8*8)
//
// Atomic-free 3-phase (R5 post-mortem: fused finalize loses; R1/R4 delta
// implicates the fp32 atomic tail inside pass1):
//   pass1: 6 strips x 128 chunks; per-thread column partial -> plain f32x4
//          store into partial[chunk][col4]; per-block ssq -> ssq_arr[bid].
//   pass2a: 6 blocks; thread j sums 128 chunk-partials of its f4-column,
//          dot-partial -> block reduce -> dotpart[block]; block 0 also
//          reduces ssq_arr.
//   pass2b: 1 block; combine scalars -> loss.
// No memset, no atomics; inter-dispatch coherence covers visibility.

typedef float f32x4 __attribute__((ext_vector_type(4)));

constexpr int COLS   = 6144;       // k * dim_emb = 8 * 768
constexpr int COLS4  = COLS / 4;   // 1536 float4 per row
constexpr int BLK    = 256;
constexpr int STRIPS = COLS4 / BLK;        // 6 column strips
constexpr int ROWS_PER_CHUNK = 64;
constexpr int CHUNKS = 8192 / ROWS_PER_CHUNK;  // 128
constexpr int NBLK1  = STRIPS * CHUNKS;        // 768

// ws layout (floats):
//   [0, CHUNKS*COLS4*4)            partial   (f32x4[CHUNKS][COLS4], 3 MB)
//   PART_F = CHUNKS*COLS4*4
constexpr size_t PART_F = (size_t)CHUNKS * COLS4 * 4;   // 786432 floats
//   [PART_F, PART_F+NBLK1)         ssq_arr
//   [PART_F+NBLK1, +6)             dotpart
//   [PART_F+NBLK1+6]               ssqsum
constexpr size_t SSQ_F  = PART_F;
constexpr size_t DOT_F  = PART_F + NBLK1;
constexpr size_t SSQS_F = DOT_F + STRIPS;

__global__ void __launch_bounds__(BLK)
anchor_pass1(const f32x4* __restrict__ a,
             f32x4* __restrict__ partial,
             float* __restrict__ ssq_arr) {
    const int col4  = blockIdx.x * BLK + threadIdx.x;   // 0..COLS4-1
    const int chunk = blockIdx.y;
    const f32x4* p = a + (size_t)chunk * ROWS_PER_CHUNK * COLS4 + col4;

    f32x4 cs = (f32x4)(0.f);
    float ssq = 0.f;
    #pragma unroll 8
    for (int r = 0; r < ROWS_PER_CHUNK; ++r) {
        f32x4 v = p[(size_t)r * COLS4];
        cs += v;
        ssq = fmaf(v.x, v.x, ssq);
        ssq = fmaf(v.y, v.y, ssq);
        ssq = fmaf(v.z, v.z, ssq);
        ssq = fmaf(v.w, v.w, ssq);
    }

    partial[(size_t)chunk * COLS4 + col4] = cs;

    #pragma unroll
    for (int off = 32; off > 0; off >>= 1)
        ssq += __shfl_down(ssq, off, 64);
    __shared__ float wsum[BLK / 64];
    const int lane = threadIdx.x & 63, wid = threadIdx.x >> 6;
    if (lane == 0) wsum[wid] = ssq;
    __syncthreads();
    if (threadIdx.x == 0) {
        float s = 0.f;
        #pragma unroll
        for (int w = 0; w < BLK / 64; ++w) s += wsum[w];
        ssq_arr[blockIdx.y * STRIPS + blockIdx.x] = s;
    }
}

__global__ void __launch_bounds__(BLK)
anchor_pass2a(const f32x4* __restrict__ partial,
              const float* __restrict__ ssq_arr,
              float* __restrict__ dotpart,
              float* __restrict__ ssqsum) {
    const int j = blockIdx.x * BLK + threadIdx.x;   // f4-column 0..1535
    f32x4 cs = (f32x4)(0.f);
    #pragma unroll 8
    for (int c = 0; c < CHUNKS; ++c)
        cs += partial[(size_t)c * COLS4 + j];
    float dot = cs.x * cs.x + cs.y * cs.y + cs.z * cs.z + cs.w * cs.w;

    __shared__ float wsum[BLK / 64];
    const int lane = threadIdx.x & 63, wid = threadIdx.x >> 6;
    #pragma unroll
    for (int off = 32; off > 0; off >>= 1)
        dot += __shfl_down(dot, off, 64);
    if (lane == 0) wsum[wid] = dot;
    __syncthreads();
    if (threadIdx.x == 0) {
        float d = 0.f;
        #pragma unroll
        for (int w = 0; w < BLK / 64; ++w) d += wsum[w];
        dotpart[blockIdx.x] = d;
    }

    if (blockIdx.x == 0) {
        __syncthreads();                 // reuse wsum safely
        float s = 0.f;
        for (int i = threadIdx.x; i < NBLK1; i += BLK) s += ssq_arr[i];
        #pragma unroll
        for (int off = 32; off > 0; off >>= 1)
            s += __shfl_down(s, off, 64);
        if (lane == 0) wsum[wid] = s;
        __syncthreads();
        if (threadIdx.x == 0) {
            float t = 0.f;
            #pragma unroll
            for (int w = 0; w < BLK / 64; ++w) t += wsum[w];
            ssqsum[0] = t;
        }
    }
}

__global__ void __launch_bounds__(64)
anchor_pass2b(const float* __restrict__ dotpart,
              const float* __restrict__ ssqsum,
              float* __restrict__ out, int n_rows) {
    if (threadIdx.x == 0) {
        float dot = 0.f;
        #pragma unroll
        for (int i = 0; i < STRIPS; ++i) dot += dotpart[i];
        double pair = 2.0 * (double)n_rows * (double)ssqsum[0]
                    - 2.0 * (double)dot;
        const double factor = 27.712812921102035;  // sqrt(768)
        out[0] = (float)(-(pair / factor) / 64.0); // k*k = 64
    }
}

extern "C" void kernel_launch(void* const* d_in, const int* in_sizes, int n_in,
                              void* d_out, int out_size, void* d_ws, size_t ws_size,
                              hipStream_t stream) {
    const f32x4* a = (const f32x4*)d_in[0];
    float* ws      = (float*)d_ws;
    float* out     = (float*)d_out;
    const int n_rows = in_sizes[0] / COLS;  // 8192

    f32x4* partial = (f32x4*)ws;
    float* ssq_arr = ws + SSQ_F;
    float* dotpart = ws + DOT_F;
    float* ssqsum  = ws + SSQS_F;

    dim3 grid1(STRIPS, CHUNKS);
    anchor_pass1<<<grid1, BLK, 0, stream>>>(a, partial, ssq_arr);
    anchor_pass2a<<<STRIPS, BLK, 0, stream>>>(partial, ssq_arr, dotpart, ssqsum);
    anchor_pass2b<<<1, 64, 0, stream>>>(dotpart, ssqsum, out, n_rows);
}